// Round 1
// baseline (1974.356 us; speedup 1.0000x reference)
//
#include <hip/hip_runtime.h>
#include <math.h>

#define SCOPE_AGENT __HIP_MEMORY_SCOPE_AGENT

__device__ __forceinline__ float sigmoidf_(float x) { return 1.0f / (1.0f + expf(-x)); }
__device__ __forceinline__ float dot4_(float4 a, float4 b) {
    return a.x * b.x + a.y * b.y + a.z * b.z + a.w * b.w;
}

// ---------------------------------------------------------------------------
// K1: 8 independent constant-input LSTM chains (128 steps each).
// Grid: 128 blocks = 8 directions x 16 WGs. Each WG owns 32 hidden units.
// Thread t: row r = t>>1 (unit u = r>>2, gate = r&3), column half = t&1
// (256 cols). Weights (256 floats) live in VGPRs. h exchanged via ws with
// agent-scope atomics + per-direction arrive/release barrier.
// ---------------------------------------------------------------------------
extern "C" __global__ __launch_bounds__(256, 1)
void lstm_k(const float* __restrict__ qWhh, const float* __restrict__ qbih,
            const float* __restrict__ qbhh, const float* __restrict__ eWhh,
            const float* __restrict__ ebih, const float* __restrict__ ebhh,
            float* __restrict__ h_glob, int* __restrict__ arrive,
            int* __restrict__ release)
{
    const int b    = blockIdx.x;
    const int d    = b >> 4;    // direction 0..7
    const int wg   = b & 15;    // workgroup within direction
    const int t    = threadIdx.x;
    const int r    = t >> 1;    // 0..127
    const int half = t & 1;
    const int u    = r >> 2;    // local unit 0..31
    const int gate = r & 3;
    const int gu   = wg * 32 + u;          // global unit 0..511
    const int wrow = gate * 512 + gu;      // row of Whh [2048 x 512]

    const float *Whh, *bih, *bhh;
    if (d < 2) {
        Whh = qWhh + (size_t)d * 2048 * 512;
        bih = qbih + d * 2048;
        bhh = qbhh + d * 2048;
    } else {
        Whh = eWhh + (size_t)(d - 2) * 2048 * 512;
        bih = ebih + (d - 2) * 2048;
        bhh = ebhh + (d - 2) * 2048;
    }

    // load this thread's 256 weight columns into registers (one-time)
    float4 w4[64];
    {
        const float4* wr = (const float4*)(Whh + (size_t)wrow * 512 + half * 256);
        #pragma unroll
        for (int k = 0; k < 64; k++) w4[k] = wr[k];
    }

    const bool leader = ((t & 7) == 0);    // one per unit (gate==0, half==0)
    float pre_i = 0.f, pre_f = 0.f, pre_g = 0.f, pre_o = 0.f, c = 0.f;
    if (leader) {
        pre_i = bih[0 * 512 + gu] + bhh[0 * 512 + gu];
        pre_f = bih[1 * 512 + gu] + bhh[1 * 512 + gu];
        pre_g = bih[2 * 512 + gu] + bhh[2 * 512 + gu];
        pre_o = bih[3 * 512 + gu] + bhh[3 * 512 + gu];
    }

    __shared__ __align__(16) float h_lds[512];
    float* hg  = h_glob + d * 512;
    int*   arr = arrive  + d * 64;   // 256B stride between directions
    int*   rel = release + d * 64;

    h_lds[t]       = 0.f;   // h_0 = 0
    h_lds[t + 256] = 0.f;
    __syncthreads();

    const int lanebase = (t & 63) & ~7;

    for (int step = 1; step <= 128; step++) {
        // partial dot: my row, my 256 columns
        const float4* hv4 = (const float4*)(h_lds + half * 256);
        float s = 0.f;
        #pragma unroll
        for (int k = 0; k < 64; k++) {
            float4 h4 = hv4[k];
            float4 ww = w4[k];
            s += ww.x * h4.x + ww.y * h4.y + ww.z * h4.z + ww.w * h4.w;
        }
        s += __shfl_xor(s, 1, 64);   // combine the two column halves

        // gather the unit's 4 gate sums (lanes base+0/2/4/6, same wave)
        float gI = __shfl(s, lanebase + 0, 64);
        float gF = __shfl(s, lanebase + 2, 64);
        float gG = __shfl(s, lanebase + 4, 64);
        float gO = __shfl(s, lanebase + 6, 64);

        if (leader) {
            float ii = sigmoidf_(pre_i + gI);
            float ff = sigmoidf_(pre_f + gF);
            float gg = tanhf(pre_g + gG);
            float oo = sigmoidf_(pre_o + gO);
            c = ff * c + ii * gg;
            float hh = oo * tanhf(c);
            __hip_atomic_store(&hg[gu], hh, __ATOMIC_RELAXED, SCOPE_AGENT);
        }
        __threadfence();     // h stores globally visible before arrival
        __syncthreads();

        if (t == 0) {
            int prev = __hip_atomic_fetch_add(arr, 1, __ATOMIC_ACQ_REL, SCOPE_AGENT);
            if (prev == 15) {            // last of the direction's 16 WGs
                __hip_atomic_store(arr, 0, __ATOMIC_RELAXED, SCOPE_AGENT);
                __hip_atomic_fetch_add(rel, 1, __ATOMIC_RELEASE, SCOPE_AGENT);
            }
            while (__hip_atomic_load(rel, __ATOMIC_ACQUIRE, SCOPE_AGENT) < step) {
                __builtin_amdgcn_s_sleep(1);
            }
        }
        __syncthreads();

        // stage fresh h (agent-scope loads bypass stale caches)
        h_lds[t]       = __hip_atomic_load(&hg[t],       __ATOMIC_RELAXED, SCOPE_AGENT);
        h_lds[t + 256] = __hip_atomic_load(&hg[t + 256], __ATOMIC_RELAXED, SCOPE_AGENT);
        __syncthreads();
    }
    // final h for this direction is in h_glob[d*512 .. +512)
}

// ---------------------------------------------------------------------------
// K2: gi[hop][row] = gru_W_ih[row,:] . r_hop + gru_b_ih[row], hop=0..2
// r_hop = h_glob[(2+2*hop)*512 .. +1024). One wave per row.
// ---------------------------------------------------------------------------
extern "C" __global__ void gi_k(const float* __restrict__ Wih, const float* __restrict__ bih,
                                const float* __restrict__ h_glob, float* __restrict__ gi)
{
    const int t = threadIdx.x;
    const int waveId = (blockIdx.x * 256 + t) >> 6;
    const int lane = t & 63;
    const int nw = gridDim.x * 4;
    for (int row = waveId; row < 3072; row += nw) {
        const float4* wr = (const float4*)(Wih + (size_t)row * 1024 + lane * 16);
        float4 w0 = wr[0], w1 = wr[1], w2 = wr[2], w3 = wr[3];
        float acc0, acc1, acc2;
        {
            const float4* rv = (const float4*)(h_glob + 2 * 512 + lane * 16);
            acc0 = dot4_(w0, rv[0]) + dot4_(w1, rv[1]) + dot4_(w2, rv[2]) + dot4_(w3, rv[3]);
        }
        {
            const float4* rv = (const float4*)(h_glob + 4 * 512 + lane * 16);
            acc1 = dot4_(w0, rv[0]) + dot4_(w1, rv[1]) + dot4_(w2, rv[2]) + dot4_(w3, rv[3]);
        }
        {
            const float4* rv = (const float4*)(h_glob + 6 * 512 + lane * 16);
            acc2 = dot4_(w0, rv[0]) + dot4_(w1, rv[1]) + dot4_(w2, rv[2]) + dot4_(w3, rv[3]);
        }
        #pragma unroll
        for (int o = 32; o > 0; o >>= 1) {
            acc0 += __shfl_xor(acc0, o, 64);
            acc1 += __shfl_xor(acc1, o, 64);
            acc2 += __shfl_xor(acc2, o, 64);
        }
        if (lane == 0) {
            float bb = bih[row];
            gi[0 * 3072 + row] = acc0 + bb;
            gi[1 * 3072 + row] = acc1 + bb;
            gi[2 * 3072 + row] = acc2 + bb;
        }
    }
}

// ---------------------------------------------------------------------------
// K3a: gh[row] = gru_W_hh[row,:] . mem + gru_b_hh[row]
// ---------------------------------------------------------------------------
extern "C" __global__ void gh_k(const float* __restrict__ Whh, const float* __restrict__ bhh,
                                const float* __restrict__ mem, float* __restrict__ gh)
{
    const int t = threadIdx.x;
    const int waveId = (blockIdx.x * 256 + t) >> 6;
    const int lane = t & 63;
    const int nw = gridDim.x * 4;
    for (int row = waveId; row < 3072; row += nw) {
        const float4* wr = (const float4*)(Whh + (size_t)row * 1024 + lane * 16);
        const float4* mv = (const float4*)(mem + lane * 16);
        float acc = dot4_(wr[0], mv[0]) + dot4_(wr[1], mv[1]) +
                    dot4_(wr[2], mv[2]) + dot4_(wr[3], mv[3]);
        #pragma unroll
        for (int o = 32; o > 0; o >>= 1) acc += __shfl_xor(acc, o, 64);
        if (lane == 0) gh[row] = acc + bhh[row];
    }
}

// ---------------------------------------------------------------------------
// K3b: GRU gate update (1 WG). memNew may alias memPrev (safe: same-index
// read-then-write per thread).
// ---------------------------------------------------------------------------
extern "C" __global__ void upd_k(const float* __restrict__ gi, const float* __restrict__ gh,
                                 const float* memPrev, float* memNew)
{
    const int t = threadIdx.x;
    for (int j = t; j < 1024; j += 256) {
        float rr = sigmoidf_(gi[j] + gh[j]);
        float zz = sigmoidf_(gi[1024 + j] + gh[1024 + j]);
        float nn = tanhf(gi[2048 + j] + rr * gh[2048 + j]);
        memNew[j] = (1.f - zz) * nn + zz * memPrev[j];
    }
}

// ---------------------------------------------------------------------------
// K4a: avec = relu(ans_W1 @ mem + ans_b1), 512 rows, one wave per row
// ---------------------------------------------------------------------------
extern "C" __global__ void ans1_k(const float* __restrict__ W1, const float* __restrict__ b1,
                                  const float* __restrict__ mem, float* __restrict__ avec)
{
    const int t = threadIdx.x;
    const int waveId = (blockIdx.x * 256 + t) >> 6;
    const int lane = t & 63;
    const int nw = gridDim.x * 4;
    for (int row = waveId; row < 512; row += nw) {
        const float4* wr = (const float4*)(W1 + (size_t)row * 1024 + lane * 16);
        const float4* mv = (const float4*)(mem + lane * 16);
        float acc = dot4_(wr[0], mv[0]) + dot4_(wr[1], mv[1]) +
                    dot4_(wr[2], mv[2]) + dot4_(wr[3], mv[3]);
        #pragma unroll
        for (int o = 32; o > 0; o >>= 1) acc += __shfl_xor(acc, o, 64);
        if (lane == 0) avec[row] = fmaxf(acc + b1[row], 0.f);
    }
}

// ---------------------------------------------------------------------------
// K4b: logits = ans_W2 @ avec + ans_b2 (32000 rows), plus the three uniform
// attention outputs (exactly 1/256 each — softmax of identical scores).
// ---------------------------------------------------------------------------
extern "C" __global__ void ans2_k(const float* __restrict__ W2, const float* __restrict__ b2,
                                  const float* __restrict__ avec, float* __restrict__ out)
{
    const int t = threadIdx.x;
    if (blockIdx.x == 0) {
        out[t]       = 1.0f / 256.0f;
        out[t + 256] = 1.0f / 256.0f;
        out[t + 512] = 1.0f / 256.0f;
    }
    const int waveId = (blockIdx.x * 256 + t) >> 6;
    const int lane = t & 63;
    const int nw = gridDim.x * 4;
    const float4* av = (const float4*)(avec + lane * 8);
    float4 a0 = av[0], a1 = av[1];
    for (int row = waveId; row < 32000; row += nw) {
        const float4* wr = (const float4*)(W2 + (size_t)row * 512 + lane * 8);
        float acc = dot4_(wr[0], a0) + dot4_(wr[1], a1);
        #pragma unroll
        for (int o = 32; o > 0; o >>= 1) acc += __shfl_xor(acc, o, 64);
        if (lane == 0) out[768 + row] = acc + b2[row];
    }
}

// ---------------------------------------------------------------------------
extern "C" void kernel_launch(void* const* d_in, const int* in_sizes, int n_in,
                              void* d_out, int out_size, void* d_ws, size_t ws_size,
                              hipStream_t stream)
{
    (void)in_sizes; (void)n_in; (void)out_size; (void)ws_size;
    // d_in[0] query_W_ih  (unused: inputs are all-zero embeddings)
    const float* qWhh = (const float*)d_in[1];
    const float* qbih = (const float*)d_in[2];
    const float* qbhh = (const float*)d_in[3];
    // d_in[4] ent_W_ih (unused)
    const float* eWhh = (const float*)d_in[5];
    const float* ebih = (const float*)d_in[6];
    const float* ebhh = (const float*)d_in[7];
    // d_in[8] sim_W, d_in[9] sim_b (unused: softmax of identical scores is uniform)
    const float* gWih = (const float*)d_in[10];
    const float* gWhh = (const float*)d_in[11];
    const float* gbih = (const float*)d_in[12];
    const float* gbhh = (const float*)d_in[13];
    const float* aW1  = (const float*)d_in[14];
    const float* ab1  = (const float*)d_in[15];
    const float* aW2  = (const float*)d_in[16];
    const float* ab2  = (const float*)d_in[17];
    // d_in[18] query_ids, d_in[19] entity_ids, d_in[20] num_entities (unused)
    float* out = (float*)d_out;

    char* ws = (char*)d_ws;
    float* h_glob  = (float*)(ws);           // 8 x 512 fp32 = 16KB
    int*   arrive  = (int*)(ws + 16384);     // 8 x 64 ints  = 2KB
    int*   release = (int*)(ws + 18432);     // 8 x 64 ints  = 2KB
    float* memory  = (float*)(ws + 20480);   // 1024 fp32    = 4KB
    float* gi      = (float*)(ws + 24576);   // 3 x 3072 fp32 = 36KB
    float* gh      = (float*)(ws + 61440);   // 3072 fp32    = 12KB
    float* avec    = (float*)(ws + 73728);   // 512 fp32     = 2KB

    // zero h (h_0 = 0) and the barrier counters
    hipMemsetAsync(d_ws, 0, 20480, stream);

    hipLaunchKernelGGL(lstm_k, dim3(128), dim3(256), 0, stream,
                       qWhh, qbih, qbhh, eWhh, ebih, ebhh, h_glob, arrive, release);

    hipLaunchKernelGGL(gi_k, dim3(192), dim3(256), 0, stream, gWih, gbih, h_glob, gi);

    for (int hop = 0; hop < 3; hop++) {
        const float* memPrev = (hop == 0) ? h_glob : memory;  // initial memory = [h_d0, h_d1]
        hipLaunchKernelGGL(gh_k, dim3(192), dim3(256), 0, stream, gWhh, gbhh, memPrev, gh);
        hipLaunchKernelGGL(upd_k, dim3(1), dim3(256), 0, stream,
                           gi + hop * 3072, gh, memPrev, memory);
    }

    hipLaunchKernelGGL(ans1_k, dim3(32), dim3(256), 0, stream, aW1, ab1, memory, avec);
    hipLaunchKernelGGL(ans2_k, dim3(256), dim3(256), 0, stream, aW2, ab2, avec, out);
}

// Round 2
// 842.842 us; speedup vs baseline: 2.3425x; 2.3425x over previous
//
#include <hip/hip_runtime.h>
#include <math.h>

#define SCOPE_AGENT __HIP_MEMORY_SCOPE_AGENT

__device__ __forceinline__ float sigmoidf_(float x) { return 1.0f / (1.0f + expf(-x)); }
__device__ __forceinline__ float dot4_(float4 a, float4 b) {
    return a.x * b.x + a.y * b.y + a.z * b.z + a.w * b.w;
}

// ---------------------------------------------------------------------------
// K1: 8 independent constant-input LSTM chains (128 steps each).
// Grid: 128 blocks = 8 directions x 16 WGs, 512 threads each.
// WG wg owns 32 hidden units (128 rows of Whh). Thread t: row_local = t>>2
// (gate = row_local>>5, unit = row_local&31), column quarter q = t&3
// (128 cols). Weights: 128 floats/thread = 128 VGPRs -> register resident
// (under the 256 arch-VGPR cap; R1's 256-float version spilled to reloads).
// Cross-WG sync: single-hop distributed stamp barrier (monotonic step
// stamps, one release store + one pipelined 16-load poll + one acquire
// fence). No per-thread threadfence (R1's 13.9us/step killer).
// ---------------------------------------------------------------------------
extern "C" __global__ __launch_bounds__(512, 1)
void lstm_k(const float* __restrict__ qWhh, const float* __restrict__ qbih,
            const float* __restrict__ qbhh, const float* __restrict__ eWhh,
            const float* __restrict__ ebih, const float* __restrict__ ebhh,
            float* __restrict__ h_glob, int* __restrict__ stamps)
{
    const int b    = blockIdx.x;
    const int d    = b >> 4;    // direction 0..7
    const int wg   = b & 15;    // workgroup within direction
    const int t    = threadIdx.x;
    const int row_local = t >> 2;        // 0..127
    const int q    = t & 3;              // column quarter
    const int gate = row_local >> 5;     // 0..3 (i,f,g,o)
    const int ulocal = row_local & 31;
    const int gu   = wg * 32 + ulocal;   // global unit 0..511
    const int wrow = gate * 512 + gu;    // row of Whh [2048 x 512]

    const float *Whh, *bih, *bhh;
    if (d < 2) {
        Whh = qWhh + (size_t)d * 2048 * 512;
        bih = qbih + d * 2048;
        bhh = qbhh + d * 2048;
    } else {
        Whh = eWhh + (size_t)(d - 2) * 2048 * 512;
        bih = ebih + (d - 2) * 2048;
        bhh = ebhh + (d - 2) * 2048;
    }

    // 128 weight columns into registers (one-time, stays resident)
    float4 w4[32];
    {
        const float4* wr = (const float4*)(Whh + (size_t)wrow * 512 + q * 128);
        #pragma unroll
        for (int k = 0; k < 32; k++) w4[k] = wr[k];
    }

    // per-unit state (threads t<32 own unit gu = wg*32 + t)
    float pre_i = 0.f, pre_f = 0.f, pre_g = 0.f, pre_o = 0.f, c = 0.f;
    if (t < 32) {
        int g2 = wg * 32 + t;
        pre_i = bih[0 * 512 + g2] + bhh[0 * 512 + g2];
        pre_f = bih[1 * 512 + g2] + bhh[1 * 512 + g2];
        pre_g = bih[2 * 512 + g2] + bhh[2 * 512 + g2];
        pre_o = bih[3 * 512 + g2] + bhh[3 * 512 + g2];
    }

    // LDS: h staged as 4 quarter-replicas padded +4 floats so the four
    // broadcast addresses land on distinct bank quads (0/4/8/12).
    __shared__ __align__(16) float h_rep[4 * 132];
    __shared__ float grow[128];

    float* hg = h_glob + d * 512;
    int*   st = stamps + d * 16;

    // h_0 = 0
    if (t < 128) {
        h_rep[0 * 132 + t] = 0.f;
        h_rep[1 * 132 + t] = 0.f;
        h_rep[2 * 132 + t] = 0.f;
        h_rep[3 * 132 + t] = 0.f;
    }
    __syncthreads();

    for (int step = 1; step <= 128; step++) {
        // partial dot: my row, my 128 columns (broadcast reads, conflict-free)
        const float4* hv = (const float4*)(h_rep + q * 132);
        float s = 0.f;
        #pragma unroll
        for (int k = 0; k < 32; k++) {
            float4 h4 = hv[k];
            float4 ww = w4[k];
            s += ww.x * h4.x + ww.y * h4.y + ww.z * h4.z + ww.w * h4.w;
        }
        s += __shfl_xor(s, 1, 64);   // combine quarters (4 consecutive lanes)
        s += __shfl_xor(s, 2, 64);
        if (q == 0) grow[row_local] = s;
        __syncthreads();

        if (t < 32) {
            float gI = grow[t];
            float gF = grow[32 + t];
            float gG = grow[64 + t];
            float gO = grow[96 + t];
            float ii = sigmoidf_(pre_i + gI);
            float ff = sigmoidf_(pre_f + gF);
            float gg = tanhf(pre_g + gG);
            float oo = sigmoidf_(pre_o + gO);
            c = ff * c + ii * gg;
            float hh = oo * tanhf(c);
            __hip_atomic_store(&hg[wg * 32 + t], hh, __ATOMIC_RELAXED, SCOPE_AGENT);
        }
        __syncthreads();   // wave0's h stores drained (s_waitcnt) before stamp

        if (t == 0) {
            // publish my WG's arrival (release covers the h stores via the
            // barrier-fence -> release transitivity)
            __hip_atomic_store(&st[wg], step, __ATOMIC_RELEASE, SCOPE_AGENT);
            // single-round-trip pipelined poll of all 16 stamps
            for (;;) {
                int mn = 0x7fffffff;
                #pragma unroll
                for (int i = 0; i < 16; i++) {
                    int v = __hip_atomic_load(&st[i], __ATOMIC_RELAXED, SCOPE_AGENT);
                    mn = (v < mn) ? v : mn;
                }
                if (mn >= step) break;
                __builtin_amdgcn_s_sleep(1);
            }
            __builtin_amdgcn_fence(__ATOMIC_ACQUIRE, "agent");
        }
        __syncthreads();

        // stage fresh h into padded quarter-replicas (1 load + 1 LDS write/thread)
        float hvn = __hip_atomic_load(&hg[t], __ATOMIC_RELAXED, SCOPE_AGENT);
        h_rep[(t >> 7) * 132 + (t & 127)] = hvn;
        __syncthreads();
    }
    // final h for this direction is in h_glob[d*512 .. +512)
}

// ---------------------------------------------------------------------------
// K2: gi[hop][row] = gru_W_ih[row,:] . r_hop + gru_b_ih[row], hop=0..2
// r_hop = h_glob[(2+2*hop)*512 .. +1024). One wave per row.
// ---------------------------------------------------------------------------
extern "C" __global__ void gi_k(const float* __restrict__ Wih, const float* __restrict__ bih,
                                const float* __restrict__ h_glob, float* __restrict__ gi)
{
    const int t = threadIdx.x;
    const int waveId = (blockIdx.x * 256 + t) >> 6;
    const int lane = t & 63;
    const int nw = gridDim.x * 4;
    for (int row = waveId; row < 3072; row += nw) {
        const float4* wr = (const float4*)(Wih + (size_t)row * 1024 + lane * 16);
        float4 w0 = wr[0], w1 = wr[1], w2 = wr[2], w3 = wr[3];
        float acc0, acc1, acc2;
        {
            const float4* rv = (const float4*)(h_glob + 2 * 512 + lane * 16);
            acc0 = dot4_(w0, rv[0]) + dot4_(w1, rv[1]) + dot4_(w2, rv[2]) + dot4_(w3, rv[3]);
        }
        {
            const float4* rv = (const float4*)(h_glob + 4 * 512 + lane * 16);
            acc1 = dot4_(w0, rv[0]) + dot4_(w1, rv[1]) + dot4_(w2, rv[2]) + dot4_(w3, rv[3]);
        }
        {
            const float4* rv = (const float4*)(h_glob + 6 * 512 + lane * 16);
            acc2 = dot4_(w0, rv[0]) + dot4_(w1, rv[1]) + dot4_(w2, rv[2]) + dot4_(w3, rv[3]);
        }
        #pragma unroll
        for (int o = 32; o > 0; o >>= 1) {
            acc0 += __shfl_xor(acc0, o, 64);
            acc1 += __shfl_xor(acc1, o, 64);
            acc2 += __shfl_xor(acc2, o, 64);
        }
        if (lane == 0) {
            float bb = bih[row];
            gi[0 * 3072 + row] = acc0 + bb;
            gi[1 * 3072 + row] = acc1 + bb;
            gi[2 * 3072 + row] = acc2 + bb;
        }
    }
}

// ---------------------------------------------------------------------------
// K3a: gh[row] = gru_W_hh[row,:] . mem + gru_b_hh[row]
// ---------------------------------------------------------------------------
extern "C" __global__ void gh_k(const float* __restrict__ Whh, const float* __restrict__ bhh,
                                const float* __restrict__ mem, float* __restrict__ gh)
{
    const int t = threadIdx.x;
    const int waveId = (blockIdx.x * 256 + t) >> 6;
    const int lane = t & 63;
    const int nw = gridDim.x * 4;
    for (int row = waveId; row < 3072; row += nw) {
        const float4* wr = (const float4*)(Whh + (size_t)row * 1024 + lane * 16);
        const float4* mv = (const float4*)(mem + lane * 16);
        float acc = dot4_(wr[0], mv[0]) + dot4_(wr[1], mv[1]) +
                    dot4_(wr[2], mv[2]) + dot4_(wr[3], mv[3]);
        #pragma unroll
        for (int o = 32; o > 0; o >>= 1) acc += __shfl_xor(acc, o, 64);
        if (lane == 0) gh[row] = acc + bhh[row];
    }
}

// ---------------------------------------------------------------------------
// K3b: GRU gate update (1 WG). memNew may alias memPrev (safe: same-index
// read-then-write per thread).
// ---------------------------------------------------------------------------
extern "C" __global__ void upd_k(const float* __restrict__ gi, const float* __restrict__ gh,
                                 const float* memPrev, float* memNew)
{
    const int t = threadIdx.x;
    for (int j = t; j < 1024; j += 256) {
        float rr = sigmoidf_(gi[j] + gh[j]);
        float zz = sigmoidf_(gi[1024 + j] + gh[1024 + j]);
        float nn = tanhf(gi[2048 + j] + rr * gh[2048 + j]);
        memNew[j] = (1.f - zz) * nn + zz * memPrev[j];
    }
}

// ---------------------------------------------------------------------------
// K4a: avec = relu(ans_W1 @ mem + ans_b1), 512 rows, one wave per row
// ---------------------------------------------------------------------------
extern "C" __global__ void ans1_k(const float* __restrict__ W1, const float* __restrict__ b1,
                                  const float* __restrict__ mem, float* __restrict__ avec)
{
    const int t = threadIdx.x;
    const int waveId = (blockIdx.x * 256 + t) >> 6;
    const int lane = t & 63;
    const int nw = gridDim.x * 4;
    for (int row = waveId; row < 512; row += nw) {
        const float4* wr = (const float4*)(W1 + (size_t)row * 1024 + lane * 16);
        const float4* mv = (const float4*)(mem + lane * 16);
        float acc = dot4_(wr[0], mv[0]) + dot4_(wr[1], mv[1]) +
                    dot4_(wr[2], mv[2]) + dot4_(wr[3], mv[3]);
        #pragma unroll
        for (int o = 32; o > 0; o >>= 1) acc += __shfl_xor(acc, o, 64);
        if (lane == 0) avec[row] = fmaxf(acc + b1[row], 0.f);
    }
}

// ---------------------------------------------------------------------------
// K4b: logits = ans_W2 @ avec + ans_b2 (32000 rows), plus the three uniform
// attention outputs (exactly 1/256 each — softmax of identical scores).
// ---------------------------------------------------------------------------
extern "C" __global__ void ans2_k(const float* __restrict__ W2, const float* __restrict__ b2,
                                  const float* __restrict__ avec, float* __restrict__ out)
{
    const int t = threadIdx.x;
    if (blockIdx.x == 0) {
        out[t]       = 1.0f / 256.0f;
        out[t + 256] = 1.0f / 256.0f;
        out[t + 512] = 1.0f / 256.0f;
    }
    const int waveId = (blockIdx.x * 256 + t) >> 6;
    const int lane = t & 63;
    const int nw = gridDim.x * 4;
    const float4* av = (const float4*)(avec + lane * 8);
    float4 a0 = av[0], a1 = av[1];
    for (int row = waveId; row < 32000; row += nw) {
        const float4* wr = (const float4*)(W2 + (size_t)row * 512 + lane * 8);
        float acc = dot4_(wr[0], a0) + dot4_(wr[1], a1);
        #pragma unroll
        for (int o = 32; o > 0; o >>= 1) acc += __shfl_xor(acc, o, 64);
        if (lane == 0) out[768 + row] = acc + b2[row];
    }
}

// ---------------------------------------------------------------------------
extern "C" void kernel_launch(void* const* d_in, const int* in_sizes, int n_in,
                              void* d_out, int out_size, void* d_ws, size_t ws_size,
                              hipStream_t stream)
{
    (void)in_sizes; (void)n_in; (void)out_size; (void)ws_size;
    // d_in[0] query_W_ih  (unused: inputs are all-zero embeddings)
    const float* qWhh = (const float*)d_in[1];
    const float* qbih = (const float*)d_in[2];
    const float* qbhh = (const float*)d_in[3];
    // d_in[4] ent_W_ih (unused)
    const float* eWhh = (const float*)d_in[5];
    const float* ebih = (const float*)d_in[6];
    const float* ebhh = (const float*)d_in[7];
    // d_in[8] sim_W, d_in[9] sim_b (unused: softmax of identical scores is uniform)
    const float* gWih = (const float*)d_in[10];
    const float* gWhh = (const float*)d_in[11];
    const float* gbih = (const float*)d_in[12];
    const float* gbhh = (const float*)d_in[13];
    const float* aW1  = (const float*)d_in[14];
    const float* ab1  = (const float*)d_in[15];
    const float* aW2  = (const float*)d_in[16];
    const float* ab2  = (const float*)d_in[17];
    // d_in[18] query_ids, d_in[19] entity_ids, d_in[20] num_entities (unused)
    float* out = (float*)d_out;

    char* ws = (char*)d_ws;
    float* h_glob  = (float*)(ws);           // 8 x 512 fp32 = 16KB
    int*   stamps  = (int*)(ws + 16384);     // 8 x 16 ints  = 512B
    float* memory  = (float*)(ws + 20480);   // 1024 fp32    = 4KB
    float* gi      = (float*)(ws + 24576);   // 3 x 3072 fp32 = 36KB
    float* gh      = (float*)(ws + 61440);   // 3072 fp32    = 12KB
    float* avec    = (float*)(ws + 73728);   // 512 fp32     = 2KB

    // zero h (h_0 = 0) and the stamp slots
    hipMemsetAsync(d_ws, 0, 20480, stream);

    hipLaunchKernelGGL(lstm_k, dim3(128), dim3(512), 0, stream,
                       qWhh, qbih, qbhh, eWhh, ebih, ebhh, h_glob, stamps);

    hipLaunchKernelGGL(gi_k, dim3(192), dim3(256), 0, stream, gWih, gbih, h_glob, gi);

    for (int hop = 0; hop < 3; hop++) {
        const float* memPrev = (hop == 0) ? h_glob : memory;  // initial memory = [h_d0, h_d1]
        hipLaunchKernelGGL(gh_k, dim3(192), dim3(256), 0, stream, gWhh, gbhh, memPrev, gh);
        hipLaunchKernelGGL(upd_k, dim3(1), dim3(256), 0, stream,
                           gi + hop * 3072, gh, memPrev, memory);
    }

    hipLaunchKernelGGL(ans1_k, dim3(32), dim3(256), 0, stream, aW1, ab1, memory, avec);
    hipLaunchKernelGGL(ans2_k, dim3(256), dim3(256), 0, stream, aW2, ab2, avec, out);
}

// Round 3
// 445.389 us; speedup vs baseline: 4.4329x; 1.8924x over previous
//
#include <hip/hip_runtime.h>
#include <math.h>

#define SCOPE_AGENT __HIP_MEMORY_SCOPE_AGENT
typedef unsigned long long u64;
typedef unsigned int u32;

__device__ __forceinline__ float sigmoidf_(float x) { return 1.0f / (1.0f + expf(-x)); }
__device__ __forceinline__ float dot4_(float4 a, float4 b) {
    return a.x * b.x + a.y * b.y + a.z * b.z + a.w * b.w;
}
__device__ __forceinline__ u64 pack_(float v, int tag) {
    return ((u64)(u32)tag << 32) | (u64)__float_as_uint(v);
}

// ---------------------------------------------------------------------------
// K1: 8 constant-input LSTM chains, 128 steps. 256 blocks = 8 dirs x 32 WGs,
// 512 threads. WG owns 16 units (64 rows of Whh[2048x512]); thread t: row
// rl=t>>3, col chunk cc=t&7 (64 cols) -> 64 weight floats/thread, pinned in
// VGPRs via empty asm (R2 showed the compiler legally re-loads otherwise).
// Sync: h published as (value,step) packed u64, double-buffered by step
// parity. Every thread polls its OWN unit's word — data IS the barrier.
// One LLC round trip per step instead of R2's stamp+fence 3-hop.
// ---------------------------------------------------------------------------
extern "C" __global__ __launch_bounds__(512, 1)
void lstm_k(const float* __restrict__ qWhh, const float* __restrict__ qbih,
            const float* __restrict__ qbhh, const float* __restrict__ eWhh,
            const float* __restrict__ ebih, const float* __restrict__ ebhh,
            u64* __restrict__ hbuf)
{
    const int b  = blockIdx.x;
    const int d  = b >> 5;     // direction 0..7
    const int wg = b & 31;     // WG within direction
    const int t  = threadIdx.x;
    const int rl = t >> 3;     // local row 0..63
    const int cc = t & 7;      // column chunk (64 cols)
    const int gate = rl >> 4;  // i,f,g,o
    const int ul   = rl & 15;
    const int gu   = wg * 16 + ul;        // global unit 0..511
    const int wrow = gate * 512 + gu;

    const float *Whh, *bih, *bhh;
    if (d < 2) {
        Whh = qWhh + (size_t)d * 2048 * 512;
        bih = qbih + d * 2048;
        bhh = qbhh + d * 2048;
    } else {
        Whh = eWhh + (size_t)(d - 2) * 2048 * 512;
        bih = ebih + (d - 2) * 2048;
        bhh = ebhh + (d - 2) * 2048;
    }

    // 64 weight floats into VGPRs; pin so they cannot be sunk into the loop
    float4 w4[16];
    {
        const float4* wr = (const float4*)(Whh + (size_t)wrow * 512 + cc * 64);
        #pragma unroll
        for (int k = 0; k < 16; k++) w4[k] = wr[k];
    }
    #pragma unroll
    for (int k = 0; k < 16; k++)
        asm volatile("" : "+v"(w4[k].x), "+v"(w4[k].y), "+v"(w4[k].z), "+v"(w4[k].w));

    float pre_i = 0.f, pre_f = 0.f, pre_g = 0.f, pre_o = 0.f, c = 0.f;
    if (t < 16) {
        int g2 = wg * 16 + t;
        pre_i = bih[g2]        + bhh[g2];
        pre_f = bih[512 + g2]  + bhh[512 + g2];
        pre_g = bih[1024 + g2] + bhh[1024 + g2];
        pre_o = bih[1536 + g2] + bhh[1536 + g2];
    }

    // h staged in LDS, 8 chunks of 64 padded to 68 -> conflict-free b128 reads
    __shared__ __align__(16) float h_pad[8 * 68];
    __shared__ float grow[64];
    for (int j = t; j < 8 * 68; j += 512) h_pad[j] = 0.f;
    __syncthreads();

    u64* plane0 = hbuf + d * 512;          // parity 0
    u64* plane1 = hbuf + 4096 + d * 512;   // parity 1

    for (int step = 1; step <= 128; step++) {
        const float4* hv = (const float4*)(h_pad + cc * 68);
        float s = 0.f;
        #pragma unroll
        for (int k = 0; k < 16; k++) s += dot4_(w4[k], hv[k]);
        s += __shfl_xor(s, 1, 64);
        s += __shfl_xor(s, 2, 64);
        s += __shfl_xor(s, 4, 64);
        if (cc == 0) grow[rl] = s;
        __syncthreads();

        u64* plane = (step & 1) ? plane1 : plane0;
        if (t < 16) {
            float ii = sigmoidf_(pre_i + grow[t]);
            float ff = sigmoidf_(pre_f + grow[16 + t]);
            float gg = tanhf(pre_g + grow[32 + t]);
            float oo = sigmoidf_(pre_o + grow[48 + t]);
            c = ff * c + ii * gg;
            float hh = oo * tanhf(c);
            __hip_atomic_store(&plane[wg * 16 + t], pack_(hh, step),
                               __ATOMIC_RELAXED, SCOPE_AGENT);
        }
        // every thread polls its own unit's tagged word (1 LLC RT)
        u64 w;
        for (;;) {
            w = __hip_atomic_load(&plane[t], __ATOMIC_RELAXED, SCOPE_AGENT);
            if ((int)(w >> 32) == step) break;
            __builtin_amdgcn_s_sleep(1);
        }
        h_pad[(t >> 6) * 68 + (t & 63)] = __uint_as_float((u32)w);
        __syncthreads();
    }
    // final h (step 128, parity 0) stays in hbuf plane 0
}

// ---------------------------------------------------------------------------
// K2: fused gi + 3x(gh+upd) + ans1. 64 blocks x 512 threads. Block b owns
// GRU rows {g*1024 + b*16 + j : g=0..2, j=0..15} so the gate update is
// block-local (gi/gh never materialized globally). mem exchanged between
// hops via tagged u64 words, parity-double-buffered. LDS dots use
// c*256+lane*4 chunk mapping (conflict-free minimum).
// ---------------------------------------------------------------------------
extern "C" __global__ __launch_bounds__(512, 1)
void mid_k(const float* __restrict__ gWih, const float* __restrict__ gWhh,
           const float* __restrict__ gbih, const float* __restrict__ gbhh,
           const float* __restrict__ aW1, const float* __restrict__ ab1,
           const u64* __restrict__ hbuf, u64* __restrict__ mem2,
           float* __restrict__ avec)
{
    const int b = blockIdx.x;    // 64
    const int t = threadIdx.x;   // 512
    const int wave = t >> 6, lane = t & 63;

    __shared__ __align__(16) float rst[3072];   // r vectors, 3 hops
    __shared__ __align__(16) float meml[1024];  // staged memory
    __shared__ float gil[144];
    __shared__ float ghl[48];

    // r_hop = concat(h[2+2h], h[3+2h]) = value words of hbuf[1024 + h*1024 + i]
    for (int i = t; i < 3072; i += 512)
        rst[i] = __uint_as_float((u32)hbuf[1024 + i]);
    __syncthreads();

    // gi for all 3 hops over this block's 48 rows (local to block)
    for (int r = wave; r < 144; r += 8) {
        int hop = r / 48, rr = r % 48;
        int g3 = rr >> 4, jj = rr & 15;
        int grow_g = g3 * 1024 + b * 16 + jj;
        const float* wp = gWih + (size_t)grow_g * 1024;
        const float* rp = rst + hop * 1024;
        float acc = 0.f;
        #pragma unroll
        for (int cch = 0; cch < 4; cch++) {
            float4 wv = *(const float4*)(wp + cch * 256 + lane * 4);
            float4 xv = *(const float4*)(rp + cch * 256 + lane * 4);
            acc += dot4_(wv, xv);
        }
        #pragma unroll
        for (int o = 32; o > 0; o >>= 1) acc += __shfl_xor(acc, o, 64);
        if (lane == 0) gil[r] = acc + gbih[grow_g];
    }

    for (int h = 0; h < 3; h++) {
        __syncthreads();
        // stage mem(h): hop0 = [h_dir0, h_dir1] from lstm; else poll tagged mem
        if (h == 0) {
            for (int i = t; i < 1024; i += 512)
                meml[i] = __uint_as_float((u32)hbuf[i]);
        } else {
            const u64* mp = mem2 + (size_t)((h - 1) & 1) * 1024;
            for (int i = t; i < 1024; i += 512) {
                u64 w;
                for (;;) {
                    w = __hip_atomic_load(&mp[i], __ATOMIC_RELAXED, SCOPE_AGENT);
                    if ((int)(w >> 32) == h) break;
                    __builtin_amdgcn_s_sleep(1);
                }
                meml[i] = __uint_as_float((u32)w);
            }
        }
        __syncthreads();
        // gh over this block's 48 rows
        for (int r = wave; r < 48; r += 8) {
            int g3 = r >> 4, jj = r & 15;
            int grow_g = g3 * 1024 + b * 16 + jj;
            const float* wp = gWhh + (size_t)grow_g * 1024;
            float acc = 0.f;
            #pragma unroll
            for (int cch = 0; cch < 4; cch++) {
                float4 wv = *(const float4*)(wp + cch * 256 + lane * 4);
                float4 xv = *(const float4*)(meml + cch * 256 + lane * 4);
                acc += dot4_(wv, xv);
            }
            #pragma unroll
            for (int o = 32; o > 0; o >>= 1) acc += __shfl_xor(acc, o, 64);
            if (lane == 0) ghl[r] = acc + gbhh[grow_g];
        }
        __syncthreads();
        // GRU update for this block's 16 hidden indices (torch order r,z,n)
        if (t < 16) {
            int j = b * 16 + t;
            float rr_ = sigmoidf_(gil[h * 48 + t]      + ghl[t]);
            float zz  = sigmoidf_(gil[h * 48 + 16 + t] + ghl[16 + t]);
            float nn  = tanhf(gil[h * 48 + 32 + t] + rr_ * ghl[32 + t]);
            float mnew = (1.f - zz) * nn + zz * meml[j];
            __hip_atomic_store(&mem2[(size_t)(h & 1) * 1024 + j], pack_(mnew, h + 1),
                               __ATOMIC_RELAXED, SCOPE_AGENT);
        }
    }
    __syncthreads();
    // final mem: hop 2 wrote parity 0 with tag 3
    for (int i = t; i < 1024; i += 512) {
        u64 w;
        for (;;) {
            w = __hip_atomic_load(&mem2[i], __ATOMIC_RELAXED, SCOPE_AGENT);
            if ((int)(w >> 32) == 3) break;
            __builtin_amdgcn_s_sleep(1);
        }
        meml[i] = __uint_as_float((u32)w);
    }
    __syncthreads();
    // ans1: row b*8 + wave (512 rows total)
    {
        int row = b * 8 + wave;
        const float* wp = aW1 + (size_t)row * 1024;
        float acc = 0.f;
        #pragma unroll
        for (int cch = 0; cch < 4; cch++) {
            float4 wv = *(const float4*)(wp + cch * 256 + lane * 4);
            float4 xv = *(const float4*)(meml + cch * 256 + lane * 4);
            acc += dot4_(wv, xv);
        }
        #pragma unroll
        for (int o = 32; o > 0; o >>= 1) acc += __shfl_xor(acc, o, 64);
        if (lane == 0) avec[row] = fmaxf(acc + ab1[row], 0.f);
    }
}

// ---------------------------------------------------------------------------
// K3: logits = ans_W2 @ avec + ans_b2 (32000 rows) + the three uniform
// attention outputs (softmax of identical scores = exactly 1/256).
// ---------------------------------------------------------------------------
extern "C" __global__ void ans2_k(const float* __restrict__ W2, const float* __restrict__ b2,
                                  const float* __restrict__ avec, float* __restrict__ out)
{
    const int t = threadIdx.x;
    if (blockIdx.x == 0) {
        out[t]       = 1.0f / 256.0f;
        out[t + 256] = 1.0f / 256.0f;
        out[t + 512] = 1.0f / 256.0f;
    }
    const int waveId = (blockIdx.x * 256 + t) >> 6;
    const int lane = t & 63;
    const int nw = gridDim.x * 4;
    const float4* av = (const float4*)(avec + lane * 8);
    float4 a0 = av[0], a1 = av[1];
    for (int row = waveId; row < 32000; row += nw) {
        const float4* wr = (const float4*)(W2 + (size_t)row * 512 + lane * 8);
        float acc = dot4_(wr[0], a0) + dot4_(wr[1], a1);
        #pragma unroll
        for (int o = 32; o > 0; o >>= 1) acc += __shfl_xor(acc, o, 64);
        if (lane == 0) out[768 + row] = acc + b2[row];
    }
}

// ---------------------------------------------------------------------------
extern "C" void kernel_launch(void* const* d_in, const int* in_sizes, int n_in,
                              void* d_out, int out_size, void* d_ws, size_t ws_size,
                              hipStream_t stream)
{
    (void)in_sizes; (void)n_in; (void)out_size; (void)ws_size;
    const float* qWhh = (const float*)d_in[1];
    const float* qbih = (const float*)d_in[2];
    const float* qbhh = (const float*)d_in[3];
    const float* eWhh = (const float*)d_in[5];
    const float* ebih = (const float*)d_in[6];
    const float* ebhh = (const float*)d_in[7];
    const float* gWih = (const float*)d_in[10];
    const float* gWhh = (const float*)d_in[11];
    const float* gbih = (const float*)d_in[12];
    const float* gbhh = (const float*)d_in[13];
    const float* aW1  = (const float*)d_in[14];
    const float* ab1  = (const float*)d_in[15];
    const float* aW2  = (const float*)d_in[16];
    const float* ab2  = (const float*)d_in[17];
    float* out = (float*)d_out;

    char* ws = (char*)d_ws;
    u64*   hbuf = (u64*)ws;                   // 2 parity x 8 dir x 512 x 8B = 64 KB
    u64*   mem2 = (u64*)(ws + 65536);         // 2 parity x 1024 x 8B = 16 KB
    float* avec = (float*)(ws + 81920);       // 512 fp32 = 2 KB

    // No memset needed: 0xAA poison (tag 0xAAAAAAAA) never equals a valid
    // step/hop tag, so every tagged word is written before it is consumed.

    hipLaunchKernelGGL(lstm_k, dim3(256), dim3(512), 0, stream,
                       qWhh, qbih, qbhh, eWhh, ebih, ebhh, hbuf);
    hipLaunchKernelGGL(mid_k, dim3(64), dim3(512), 0, stream,
                       gWih, gWhh, gbih, gbhh, aW1, ab1, hbuf, mem2, avec);
    hipLaunchKernelGGL(ans2_k, dim3(512), dim3(256), 0, stream, aW2, ab2, avec, out);
}